// Round 15
// baseline (296.270 us; speedup 1.0000x reference)
//
#include <hip/hip_runtime.h>

#define N_NODES 100000
#define N_EDGES 1600000
#define HIDDEN 64
#define OUT_CH 16
#define N_GRAPHS 64
#define N_TILES 6250                  // N_NODES / 16
#define SCAN_B 256
#define NB1 391                       // scan blocks; also NBUCK (100096/256)
#define NBUCK 391                     // coarse buckets (dst >> 8)
#define NN2 (NBUCK * 256)             // 100096: padded node space
#define CBLK 250                      // coarse blocks
#define EPB 6400                      // edges per coarse block (250*6400 = 1.6M)
#define W_SCALE (1.0f / 32767.0f)

typedef __attribute__((ext_vector_type(8))) short bf16x8;
typedef __attribute__((ext_vector_type(4))) float f32x4;

__device__ __forceinline__ float bfu(unsigned short u) {            // bf16 -> f32
    return __uint_as_float(((unsigned)u) << 16);
}
__device__ __forceinline__ unsigned short f2bf(float x) {           // f32 -> bf16 RTN
    unsigned u = __float_as_uint(x);
    return (unsigned short)((u + 0x7FFFu + ((u >> 16) & 1u)) >> 16);
}
// load 8 consecutive f32 of W row c starting at k0, convert to bf16x8 frag
__device__ __forceinline__ bf16x8 load_wfrag(const float* __restrict__ W, int c, int k0) {
    float4 a = *(const float4*)(W + c * 64 + k0);
    float4 b = *(const float4*)(W + c * 64 + k0 + 4);
    bf16x8 r;
    r[0] = (short)f2bf(a.x); r[1] = (short)f2bf(a.y); r[2] = (short)f2bf(a.z); r[3] = (short)f2bf(a.w);
    r[4] = (short)f2bf(b.x); r[5] = (short)f2bf(b.y); r[6] = (short)f2bf(b.z); r[7] = (short)f2bf(b.w);
    return r;
}

// ---------------------------------------------------------------------------
// Phase A1: per-block coarse-bucket histogram (LDS) -> bmat[b][blk]
__global__ __launch_bounds__(256) void k_bhist(const int* __restrict__ dst, int* __restrict__ bmat) {
    __shared__ int bh[NBUCK];
    int t = threadIdx.x, blk = blockIdx.x;
    for (int b = t; b < NBUCK; b += 256) bh[b] = 0;
    __syncthreads();
    int base = blk * EPB;
    for (int r = 0; r < EPB / 256; ++r)
        atomicAdd(&bh[dst[base + r * 256 + t] >> 8], 1);
    __syncthreads();
    for (int b = t; b < NBUCK; b += 256) bmat[b * 256 + blk] = bh[b];
}

// Phase A2: per-bucket exclusive scan over the 250 block counts (column scan)
__global__ __launch_bounds__(256) void k_colscan(int* __restrict__ bmat, int* __restrict__ btotal) {
    __shared__ int s[256];
    int b = blockIdx.x, t = threadIdx.x;
    int v = (t < CBLK) ? bmat[b * 256 + t] : 0;
    s[t] = v;
    __syncthreads();
    for (int off = 1; off < 256; off <<= 1) {
        int x = (t >= off) ? s[t - off] : 0;
        __syncthreads();
        s[t] += x;
        __syncthreads();
    }
    if (t < CBLK) bmat[b * 256 + t] = s[t] - v;   // exclusive within column
    if (t == 255) btotal[b] = s[255];
}

// Generic 391-length exclusive scan in one block (used for cbase and boff)
__global__ __launch_bounds__(512) void k_scan_bsum(const int* __restrict__ in, int* __restrict__ outp) {
    __shared__ int s[512];
    int t = threadIdx.x;
    int v = (t < NB1) ? in[t] : 0;
    s[t] = v;
    __syncthreads();
    for (int off = 1; off < 512; off <<= 1) {
        int x = (t >= off) ? s[t - off] : 0;
        __syncthreads();
        s[t] += x;
        __syncthreads();
    }
    if (t < NB1) outp[t] = s[t] - v;   // exclusive
}

// Phase A3: coarse scatter. Each (block,bucket) owns an exclusive contiguous
// run in C -> writes are short contiguous runs (L2 merges within one XCD).
__global__ __launch_bounds__(256) void k_coarse(
    const int* __restrict__ src, const int* __restrict__ dst, const float* __restrict__ w,
    const int* __restrict__ bmat, const int* __restrict__ cbase, uint2* __restrict__ C)
{
    __shared__ int cur[NBUCK];
    int t = threadIdx.x, blk = blockIdx.x;
    for (int b = t; b < NBUCK; b += 256) cur[b] = cbase[b] + bmat[b * 256 + blk];
    __syncthreads();
    int base = blk * EPB;
    for (int r = 0; r < EPB / 256; ++r) {
        int e = base + r * 256 + t;
        int d = dst[e];
        int q = __float2int_rn(w[e] * 32767.0f);
        unsigned pe = ((unsigned)src[e] << 15) | (unsigned)q;
        int pos = atomicAdd(&cur[d >> 8], 1);
        C[pos] = make_uint2(pe, (unsigned)(d & 255));
    }
}

// Phase B1: per-node counts within each bucket (coalesced region read)
__global__ __launch_bounds__(256) void k_fhist(const uint2* __restrict__ C, const int* __restrict__ cbase,
                                               const int* __restrict__ btotal, int* __restrict__ pcnt) {
    __shared__ int c[256];
    int b = blockIdx.x, t = threadIdx.x;
    c[t] = 0;
    __syncthreads();
    int j0 = cbase[b], j1 = j0 + btotal[b];
    for (int j = j0 + t; j < j1; j += 256) atomicAdd(&c[C[j].y], 1);
    __syncthreads();
    pcnt[b * 256 + t] = c[t];
}

// Phase B2a: per-block sums of PADDED counts (rows padded to multiple of 4)
__global__ __launch_bounds__(SCAN_B) void k_partial(const int* __restrict__ pcnt, int* __restrict__ bsum) {
    __shared__ int s[SCAN_B];
    int b = blockIdx.x, t = threadIdx.x;
    s[t] = (pcnt[b * SCAN_B + t] + 3) & ~3;
    __syncthreads();
    for (int off = SCAN_B / 2; off > 0; off >>= 1) {
        if (t < off) s[t] += s[t + off];
        __syncthreads();
    }
    if (t == 0) bsum[b] = s[0];
}

// Phase B2b: per-block exclusive scan of padded counts -> row_ptr
__global__ __launch_bounds__(SCAN_B) void k_scan_final(const int* __restrict__ pcnt, const int* __restrict__ boff,
                                                       int* __restrict__ row_ptr) {
    __shared__ int s[SCAN_B];
    int b = blockIdx.x, t = threadIdx.x;
    int i = b * SCAN_B + t;
    int v = (pcnt[i] + 3) & ~3;
    s[t] = v;
    __syncthreads();
    for (int off = 1; off < SCAN_B; off <<= 1) {
        int x = (t >= off) ? s[t - off] : 0;
        __syncthreads();
        s[t] += x;
        __syncthreads();
    }
    row_ptr[i] = boff[b] + s[t] - v;
    if (i == NN2 - 1) row_ptr[NN2] = boff[b] + s[t];   // padded total
}

// Phase B3: fine scatter + zero-padding + FUSED layer-1 aggregation.
__global__ __launch_bounds__(256) void k_fine(const uint2* __restrict__ C, const int* __restrict__ cbase,
                                              const int* __restrict__ btotal, const int* __restrict__ row_ptr,
                                              const float* __restrict__ x,
                                              unsigned* __restrict__ E, float2* __restrict__ p) {
    __shared__ int cur[256];
    int b = blockIdx.x, t = threadIdx.x;
    int i = b * 256 + t;
    int rp0 = row_ptr[i];
    int rp1 = row_ptr[i + 1];
    cur[t] = rp0;
    __syncthreads();
    int j0 = cbase[b], j1 = j0 + btotal[b];
    for (int j = j0 + t; j < j1; j += 256) {
        uint2 c = C[j];
        int pos = atomicAdd(&cur[c.y], 1);
        E[pos] = c.x;
    }
    __syncthreads();
    int jend = cur[t];
    for (int j = jend; j < rp1; ++j) E[j] = 0u;     // zero pad slots
    if (i < N_NODES) {
        float acc0 = 0.0f, acc1 = 0.0f;
        int j = rp0;
        unsigned e0 = (j     < jend) ? E[j]     : 0u;
        unsigned e1 = (j + 1 < jend) ? E[j + 1] : 0u;
        while (j < jend) {
            float x0 = x[e0 >> 15];
            float x1 = x[e1 >> 15];
            unsigned n0 = (j + 2 < jend) ? E[j + 2] : 0u;
            unsigned n1 = (j + 3 < jend) ? E[j + 3] : 0u;
            acc0 = fmaf((float)(e0 & 32767u) * W_SCALE, x0, acc0);
            acc1 = fmaf((float)(e1 & 32767u) * W_SCALE, x1, acc1);
            e0 = n0; e1 = n1; j += 2;
        }
        p[i] = make_float2(acc0 + acc1, x[i]);
    }
}

// ---------------------------------------------------------------------------
// Layer 2 FUSED gather+transform. Block = 256 threads = one 16-node tile.
// Gather: slot s = t>>4 owns node tile*16+s; lane q = t&15 owns channels
// 4q..4q+3 exclusively (no reduction needed); 4-deep edge pipeline.
// Result -> XOR-swizzled LDS tile. Transform: wave wv computes quadrant
// ct=wv via 4 MFMAs; h1 root term recomputed from p; h2 written bf16.
__global__ __launch_bounds__(256) void k_l2_fused(
    const int* __restrict__ rp, const unsigned* __restrict__ E,
    const float2* __restrict__ p,
    const float* __restrict__ Wr1, const float* __restrict__ b1,
    const float* __restrict__ Wo1,
    const float* __restrict__ Wrel, const float* __restrict__ brel,
    const float* __restrict__ Wroot,
    unsigned short* __restrict__ h2)
{
    __shared__ unsigned short lds[16 * 64];     // 2KB swizzled agg tile
    int t = threadIdx.x;
    int s = t >> 4, q = t & 15;
    int tile = blockIdx.x;
    int node = tile * 16 + s;
    float4 wr = *(const float4*)(Wr1 + q * 4);
    float4 wo = *(const float4*)(Wo1 + q * 4);
    float4 bb = *(const float4*)(b1  + q * 4);
    int j0 = rp[node], j1 = rp[node + 1];
    float4 a0 = make_float4(0.f, 0.f, 0.f, 0.f);
    float4 a1 = make_float4(0.f, 0.f, 0.f, 0.f);
    int j = j0;
    unsigned e0 = (j     < j1) ? E[j]     : 0u;
    unsigned e1 = (j + 1 < j1) ? E[j + 1] : 0u;
    unsigned e2 = (j + 2 < j1) ? E[j + 2] : 0u;
    unsigned e3 = (j + 3 < j1) ? E[j + 3] : 0u;
    while (j < j1) {
        float2 p0 = p[e0 >> 15];
        float2 p1 = p[e1 >> 15];
        float2 p2 = p[e2 >> 15];
        float2 p3 = p[e3 >> 15];
        unsigned n0 = (j + 4 < j1) ? E[j + 4] : 0u;
        unsigned n1 = (j + 5 < j1) ? E[j + 5] : 0u;
        unsigned n2 = (j + 6 < j1) ? E[j + 6] : 0u;
        unsigned n3 = (j + 7 < j1) ? E[j + 7] : 0u;
        float w0 = (float)(e0 & 32767u) * W_SCALE;
        float w1 = (float)(e1 & 32767u) * W_SCALE;
        float w2 = (float)(e2 & 32767u) * W_SCALE;
        float w3 = (float)(e3 & 32767u) * W_SCALE;
        a0.x = fmaf(w0, fmaxf(fmaf(p0.x, wr.x, fmaf(p0.y, wo.x, bb.x)), 0.0f), a0.x);
        a0.y = fmaf(w0, fmaxf(fmaf(p0.x, wr.y, fmaf(p0.y, wo.y, bb.y)), 0.0f), a0.y);
        a0.z = fmaf(w0, fmaxf(fmaf(p0.x, wr.z, fmaf(p0.y, wo.z, bb.z)), 0.0f), a0.z);
        a0.w = fmaf(w0, fmaxf(fmaf(p0.x, wr.w, fmaf(p0.y, wo.w, bb.w)), 0.0f), a0.w);
        a1.x = fmaf(w1, fmaxf(fmaf(p1.x, wr.x, fmaf(p1.y, wo.x, bb.x)), 0.0f), a1.x);
        a1.y = fmaf(w1, fmaxf(fmaf(p1.x, wr.y, fmaf(p1.y, wo.y, bb.y)), 0.0f), a1.y);
        a1.z = fmaf(w1, fmaxf(fmaf(p1.x, wr.z, fmaf(p1.y, wo.z, bb.z)), 0.0f), a1.z);
        a1.w = fmaf(w1, fmaxf(fmaf(p1.x, wr.w, fmaf(p1.y, wo.w, bb.w)), 0.0f), a1.w);
        a0.x = fmaf(w2, fmaxf(fmaf(p2.x, wr.x, fmaf(p2.y, wo.x, bb.x)), 0.0f), a0.x);
        a0.y = fmaf(w2, fmaxf(fmaf(p2.x, wr.y, fmaf(p2.y, wo.y, bb.y)), 0.0f), a0.y);
        a0.z = fmaf(w2, fmaxf(fmaf(p2.x, wr.z, fmaf(p2.y, wo.z, bb.z)), 0.0f), a0.z);
        a0.w = fmaf(w2, fmaxf(fmaf(p2.x, wr.w, fmaf(p2.y, wo.w, bb.w)), 0.0f), a0.w);
        a1.x = fmaf(w3, fmaxf(fmaf(p3.x, wr.x, fmaf(p3.y, wo.x, bb.x)), 0.0f), a1.x);
        a1.y = fmaf(w3, fmaxf(fmaf(p3.x, wr.y, fmaf(p3.y, wo.y, bb.y)), 0.0f), a1.y);
        a1.z = fmaf(w3, fmaxf(fmaf(p3.x, wr.z, fmaf(p3.y, wo.z, bb.z)), 0.0f), a1.z);
        a1.w = fmaf(w3, fmaxf(fmaf(p3.x, wr.w, fmaf(p3.y, wo.w, bb.w)), 0.0f), a1.w);
        e0 = n0; e1 = n1; e2 = n2; e3 = n3; j += 4;
    }
    ushort4 st;
    st.x = f2bf(a0.x + a1.x); st.y = f2bf(a0.y + a1.y);
    st.z = f2bf(a0.z + a1.z); st.w = f2bf(a0.w + a1.w);
    *(ushort4*)((char*)lds + s * 128 + ((q * 8) ^ ((s & 7) << 4))) = st;
    __syncthreads();

    // ---- transform: wave wv = quadrant ct ----
    int wv = t >> 6, l = t & 63;
    int lo = l & 15, hi = l >> 4, ct = wv;
    bf16x8 wR0 = load_wfrag(Wrel,  ct * 16 + lo, hi * 8);
    bf16x8 wR1 = load_wfrag(Wrel,  ct * 16 + lo, 32 + hi * 8);
    bf16x8 wO0 = load_wfrag(Wroot, ct * 16 + lo, hi * 8);
    bf16x8 wO1 = load_wfrag(Wroot, ct * 16 + lo, 32 + hi * 8);
    bf16x8 bA0 = *(const bf16x8*)((char*)lds + lo * 128 + ((hi * 16) ^ ((lo & 7) << 4)));
    bf16x8 bA1 = *(const bf16x8*)((char*)lds + lo * 128 + ((64 + hi * 16) ^ ((lo & 7) << 4)));
    float2 pv = p[tile * 16 + lo];
    bf16x8 bH0, bH1;
    #pragma unroll
    for (int jj = 0; jj < 8; ++jj) {
        int i0 = hi * 8 + jj, i1 = 32 + hi * 8 + jj;
        bH0[jj] = (short)f2bf(fmaxf(fmaf(pv.x, Wr1[i0], fmaf(pv.y, Wo1[i0], b1[i0])), 0.0f));
        bH1[jj] = (short)f2bf(fmaxf(fmaf(pv.x, Wr1[i1], fmaf(pv.y, Wo1[i1], b1[i1])), 0.0f));
    }
    f32x4 acc = {brel[ct * 16 + hi * 4 + 0], brel[ct * 16 + hi * 4 + 1],
                 brel[ct * 16 + hi * 4 + 2], brel[ct * 16 + hi * 4 + 3]};
    acc = __builtin_amdgcn_mfma_f32_16x16x32_bf16(wR0, bA0, acc, 0, 0, 0);
    acc = __builtin_amdgcn_mfma_f32_16x16x32_bf16(wR1, bA1, acc, 0, 0, 0);
    acc = __builtin_amdgcn_mfma_f32_16x16x32_bf16(wO0, bH0, acc, 0, 0, 0);
    acc = __builtin_amdgcn_mfma_f32_16x16x32_bf16(wO1, bH1, acc, 0, 0, 0);
    ushort4 so;
    so.x = f2bf(fmaxf(acc[0], 0.0f)); so.y = f2bf(fmaxf(acc[1], 0.0f));
    so.z = f2bf(fmaxf(acc[2], 0.0f)); so.w = f2bf(fmaxf(acc[3], 0.0f));
    *(ushort4*)(h2 + (tile * 16 + lo) * 64 + ct * 16 + hi * 4) = so;
}

// ---------------------------------------------------------------------------
// Layer 3 FUSED gather+transform+pool. Same structure; gather reads bf16 h2
// rows (lane q loads ushort4 = its 4 channels, 128B coalesced per slot);
// transform root term reads h2 directly; h3 pooled in-kernel into 16 sums
// replicas (no h3 buffer).
__global__ __launch_bounds__(256) void k_l3_fused(
    const int* __restrict__ rp, const unsigned* __restrict__ E,
    const unsigned short* __restrict__ h2,
    const float* __restrict__ Wrel, const float* __restrict__ brel,
    const float* __restrict__ Wroot, const int* __restrict__ batch,
    float* __restrict__ sums)
{
    __shared__ unsigned short lds[16 * 64];
    int t = threadIdx.x;
    int s = t >> 4, q = t & 15;
    int tile = blockIdx.x;
    int node = tile * 16 + s;
    int j0 = rp[node], j1 = rp[node + 1];
    float4 a0 = make_float4(0.f, 0.f, 0.f, 0.f);
    float4 a1 = make_float4(0.f, 0.f, 0.f, 0.f);
    int j = j0;
    unsigned e0 = (j     < j1) ? E[j]     : 0u;
    unsigned e1 = (j + 1 < j1) ? E[j + 1] : 0u;
    unsigned e2 = (j + 2 < j1) ? E[j + 2] : 0u;
    unsigned e3 = (j + 3 < j1) ? E[j + 3] : 0u;
    while (j < j1) {
        ushort4 r0 = *((const ushort4*)(h2 + (e0 >> 15) * 64) + q);
        ushort4 r1 = *((const ushort4*)(h2 + (e1 >> 15) * 64) + q);
        ushort4 r2 = *((const ushort4*)(h2 + (e2 >> 15) * 64) + q);
        ushort4 r3 = *((const ushort4*)(h2 + (e3 >> 15) * 64) + q);
        unsigned n0 = (j + 4 < j1) ? E[j + 4] : 0u;
        unsigned n1 = (j + 5 < j1) ? E[j + 5] : 0u;
        unsigned n2 = (j + 6 < j1) ? E[j + 6] : 0u;
        unsigned n3 = (j + 7 < j1) ? E[j + 7] : 0u;
        float w0 = (float)(e0 & 32767u) * W_SCALE;
        float w1 = (float)(e1 & 32767u) * W_SCALE;
        float w2 = (float)(e2 & 32767u) * W_SCALE;
        float w3 = (float)(e3 & 32767u) * W_SCALE;
        a0.x = fmaf(w0, bfu(r0.x), a0.x); a0.y = fmaf(w0, bfu(r0.y), a0.y);
        a0.z = fmaf(w0, bfu(r0.z), a0.z); a0.w = fmaf(w0, bfu(r0.w), a0.w);
        a1.x = fmaf(w1, bfu(r1.x), a1.x); a1.y = fmaf(w1, bfu(r1.y), a1.y);
        a1.z = fmaf(w1, bfu(r1.z), a1.z); a1.w = fmaf(w1, bfu(r1.w), a1.w);
        a0.x = fmaf(w2, bfu(r2.x), a0.x); a0.y = fmaf(w2, bfu(r2.y), a0.y);
        a0.z = fmaf(w2, bfu(r2.z), a0.z); a0.w = fmaf(w2, bfu(r2.w), a0.w);
        a1.x = fmaf(w3, bfu(r3.x), a1.x); a1.y = fmaf(w3, bfu(r3.y), a1.y);
        a1.z = fmaf(w3, bfu(r3.z), a1.z); a1.w = fmaf(w3, bfu(r3.w), a1.w);
        e0 = n0; e1 = n1; e2 = n2; e3 = n3; j += 4;
    }
    ushort4 st;
    st.x = f2bf(a0.x + a1.x); st.y = f2bf(a0.y + a1.y);
    st.z = f2bf(a0.z + a1.z); st.w = f2bf(a0.w + a1.w);
    *(ushort4*)((char*)lds + s * 128 + ((q * 8) ^ ((s & 7) << 4))) = st;
    __syncthreads();

    // ---- transform quadrant ct = wv ----
    int wv = t >> 6, l = t & 63;
    int lo = l & 15, hi = l >> 4, ct = wv;
    bf16x8 wR0 = load_wfrag(Wrel,  ct * 16 + lo, hi * 8);
    bf16x8 wR1 = load_wfrag(Wrel,  ct * 16 + lo, 32 + hi * 8);
    bf16x8 wO0 = load_wfrag(Wroot, ct * 16 + lo, hi * 8);
    bf16x8 wO1 = load_wfrag(Wroot, ct * 16 + lo, 32 + hi * 8);
    bf16x8 bA0 = *(const bf16x8*)((char*)lds + lo * 128 + ((hi * 16) ^ ((lo & 7) << 4)));
    bf16x8 bA1 = *(const bf16x8*)((char*)lds + lo * 128 + ((64 + hi * 16) ^ ((lo & 7) << 4)));
    bf16x8 bH0 = *(const bf16x8*)(h2 + (tile * 16 + lo) * 64 + hi * 8);
    bf16x8 bH1 = *(const bf16x8*)(h2 + (tile * 16 + lo) * 64 + 32 + hi * 8);
    f32x4 acc = {brel[ct * 16 + hi * 4 + 0], brel[ct * 16 + hi * 4 + 1],
                 brel[ct * 16 + hi * 4 + 2], brel[ct * 16 + hi * 4 + 3]};
    acc = __builtin_amdgcn_mfma_f32_16x16x32_bf16(wR0, bA0, acc, 0, 0, 0);
    acc = __builtin_amdgcn_mfma_f32_16x16x32_bf16(wR1, bA1, acc, 0, 0, 0);
    acc = __builtin_amdgcn_mfma_f32_16x16x32_bf16(wO0, bH0, acc, 0, 0, 0);
    acc = __builtin_amdgcn_mfma_f32_16x16x32_bf16(wO1, bH1, acc, 0, 0, 0);

    // ---- pool (batch sorted; boundary tiles rare) ----
    int gi = batch[tile * 16 + lo];
    int gfirst = __shfl(gi, 0);
    int glast  = __shfl(gi, 15);
    float* srep = sums + (blockIdx.x & 15) * (N_GRAPHS * 64);
    if (gfirst == glast) {
        #pragma unroll
        for (int jj = 0; jj < 4; ++jj) {
            float v = acc[jj];
            v += __shfl_xor(v, 1); v += __shfl_xor(v, 2);
            v += __shfl_xor(v, 4); v += __shfl_xor(v, 8);
            if (lo == 0) atomicAdd(&srep[gfirst * 64 + ct * 16 + hi * 4 + jj], v);
        }
    } else {
        #pragma unroll
        for (int jj = 0; jj < 4; ++jj)
            atomicAdd(&srep[gi * 64 + ct * 16 + hi * 4 + jj], acc[jj]);
    }
}

// Pool stage 2: sum 16 replicas, divide by count, 64->16 linear. One block/graph.
__global__ __launch_bounds__(64) void k_pool2(
    const float* __restrict__ sums, const int* __restrict__ batch,
    const float* __restrict__ Wlin, const float* __restrict__ blin,
    float* __restrict__ out)
{
    int g = blockIdx.x;
    int c = threadIdx.x;
    int lo = 0, hi = N_NODES;
    while (lo < hi) { int mid = (lo + hi) >> 1; if (batch[mid] < g) lo = mid + 1; else hi = mid; }
    int s0 = lo;
    lo = 0; hi = N_NODES;
    while (lo < hi) { int mid = (lo + hi) >> 1; if (batch[mid] < g + 1) lo = mid + 1; else hi = mid; }
    int s1 = lo;
    __shared__ float pooled[64];
    float acc = 0.0f;
    #pragma unroll
    for (int r = 0; r < 16; ++r) acc += sums[r * (N_GRAPHS * 64) + g * 64 + c];
    float cnt = (float)(s1 - s0);
    pooled[c] = acc / fmaxf(cnt, 1.0f);
    __syncthreads();
    if (c < OUT_CH) {
        float a2 = blin[c];
        #pragma unroll 8
        for (int k = 0; k < HIDDEN; ++k) a2 += pooled[k] * Wlin[c * 64 + k];
        out[g * OUT_CH + c] = a2;
    }
}

// ---------------------------------------------------------------------------
extern "C" void kernel_launch(void* const* d_in, const int* in_sizes, int n_in,
                              void* d_out, int out_size, void* d_ws, size_t ws_size,
                              hipStream_t stream)
{
    const float* x    = (const float*)d_in[0];
    const int*   ei   = (const int*)d_in[1];      // [2, E]: row0=src, row1=dst
    const int*   src  = ei;
    const int*   dst  = ei + N_EDGES;
    const float* ew   = (const float*)d_in[2];
    const int*   batch= (const int*)d_in[3];
    const float* Wr1  = (const float*)d_in[4];
    const float* b1   = (const float*)d_in[5];
    const float* Wo1  = (const float*)d_in[6];
    const float* Wr2  = (const float*)d_in[7];
    const float* b2   = (const float*)d_in[8];
    const float* Wo2  = (const float*)d_in[9];
    const float* Wr3  = (const float*)d_in[10];
    const float* b3   = (const float*)d_in[11];
    const float* Wo3  = (const float*)d_in[12];
    const float* Wlin = (const float*)d_in[13];
    const float* blin = (const float*)d_in[14];
    float* out = (float*)d_out;

    // workspace layout (~38 MB; 78.6 MB proven safe in round 0)
    char* ws = (char*)d_ws;
    const size_t K = 1024;
    int*            row_ptr = (int*)(ws + 0);               // 404 KB (NN2+1 ints)
    int*            bmat    = (int*)(ws + 512 * K);         // 400 KB
    int*            btotal  = (int*)(ws + 1024 * K);
    int*            cbase   = (int*)(ws + 1028 * K);
    int*            bsum    = (int*)(ws + 1032 * K);
    int*            boff    = (int*)(ws + 1036 * K);
    int*            pcnt    = (int*)(ws + 1040 * K);        // 400 KB
    float2*         p       = (float2*)(ws + 1536 * K);     // 800 KB
    uint2*          C       = (uint2*)(ws + 2560 * K);      // 12.8 MB
    unsigned*       E       = (unsigned*)(ws + 15360 * K);  // up to 7.6 MB (padded CSR)
    unsigned short* h2      = (unsigned short*)(ws + 23552 * K); // 12.8 MB
    float*          sums    = (float*)(ws + 36864 * K);     // 16 replicas x 16 KB = 256 KB

    // ---- CSR build: 3-phase counting sort ----
    hipMemsetAsync(sums, 0, 16 * N_GRAPHS * HIDDEN * sizeof(float), stream);
    k_bhist<<<CBLK, 256, 0, stream>>>(dst, bmat);
    k_colscan<<<NBUCK, 256, 0, stream>>>(bmat, btotal);
    k_scan_bsum<<<1, 512, 0, stream>>>(btotal, cbase);
    k_coarse<<<CBLK, 256, 0, stream>>>(src, dst, ew, bmat, cbase, C);
    k_fhist<<<NBUCK, 256, 0, stream>>>(C, cbase, btotal, pcnt);
    k_partial<<<NB1, SCAN_B, 0, stream>>>(pcnt, bsum);
    k_scan_bsum<<<1, 512, 0, stream>>>(bsum, boff);
    k_scan_final<<<NB1, SCAN_B, 0, stream>>>(pcnt, boff, row_ptr);
    k_fine<<<NBUCK, 256, 0, stream>>>(C, cbase, btotal, row_ptr, x, E, p);  // + pad-zero + agg1

    // ---- layer 2 fused: gather + MFMA transform -> h2 (bf16) ----
    k_l2_fused<<<N_TILES, 256, 0, stream>>>(row_ptr, E, p, Wr1, b1, Wo1, Wr2, b2, Wo2, h2);

    // ---- layer 3 fused: gather + MFMA transform + pool stage 1 ----
    k_l3_fused<<<N_TILES, 256, 0, stream>>>(row_ptr, E, h2, Wr3, b3, Wo3, batch, sums);

    // ---- pool stage 2: replica-sum, divide, 64->16 linear ----
    k_pool2<<<N_GRAPHS, 64, 0, stream>>>(sums, batch, Wlin, blin, out);
}